// Round 13
// baseline (239.492 us; speedup 1.0000x reference)
//
#include <hip/hip_runtime.h>
#include <cstdint>
#include <cstddef>

#define DEV static __device__ __forceinline__

typedef __attribute__((ext_vector_type(8))) short bf16x8;
typedef __attribute__((ext_vector_type(4))) float f32x4;
typedef __attribute__((ext_vector_type(16))) float f32x16;

#define T_SEQ 4096
#define CDIM  768
#define NH    12
#define HD    64
#define NBH   24            // B * NH
#define M_ROWS 8192         // B * T

// ---- workspace layout (bytes) ----
#define OFF_XB   0ull
#define OFF_WAT  (OFF_XB  + (size_t)M_ROWS * CDIM * 2)       // xb: [8192][768] bf16
#define OFF_WPT  (OFF_WAT + (size_t)(3*CDIM) * CDIM * 2)     // WaT: [2304][768] bf16
#define OFF_Q    (OFF_WPT + (size_t)CDIM * CDIM * 2)         // WpT: [768][768] bf16
#define OFF_K    (OFF_Q   + (size_t)NBH * T_SEQ * HD * 2)    // Q: [24][4096][64] bf16 (pre-scaled by log2e/8)
#define OFF_VT   (OFF_K   + (size_t)NBH * T_SEQ * HD * 2)    // K: [24][4096][64] bf16
#define OFF_O    (OFF_VT  + (size_t)NBH * HD * T_SEQ * 2)    // Vt: [24][64][4096] bf16 (key cols bit2<->bit3 permuted)
#define OFF_P    (OFF_O   + (size_t)M_ROWS * CDIM * 2)       // O (combined): [8192][768] bf16
#define OFF_L    (OFF_P   + 2ull * M_ROWS * CDIM * 2)        // Op partials: [2][8192][768] bf16
// Lp partials: [2][24][4096] f32

DEV unsigned short f2bf(float f) {            // RTNE f32 -> bf16
  unsigned u = __builtin_bit_cast(unsigned, f);
  u += 0x7FFFu + ((u >> 16) & 1u);
  return (unsigned short)(u >> 16);
}

DEV float bf2f(unsigned short s) {
  unsigned u = (unsigned)s << 16;
  return __builtin_bit_cast(float, u);
}

DEV void gld_lds16(const void* g, void* l) {  // async global->LDS, 16B/lane, dest = wave-uniform base + lane*16
  __builtin_amdgcn_global_load_lds(
      (const __attribute__((address_space(1))) void*)g,
      (__attribute__((address_space(3))) void*)l, 16, 0, 0);
}

// ---------------- kernel 1: cast x f32 -> bf16 ----------------
__global__ __launch_bounds__(256) void k_conv(const float* __restrict__ in,
                                              unsigned short* __restrict__ out) {
  int i = blockIdx.x * 256 + threadIdx.x;
  const float4* p = (const float4*)in;
  float4 a = p[i * 2], b = p[i * 2 + 1];
  uint4 o;
  o.x = (unsigned)f2bf(a.x) | ((unsigned)f2bf(a.y) << 16);
  o.y = (unsigned)f2bf(a.z) | ((unsigned)f2bf(a.w) << 16);
  o.z = (unsigned)f2bf(b.x) | ((unsigned)f2bf(b.y) << 16);
  o.w = (unsigned)f2bf(b.z) | ((unsigned)f2bf(b.w) << 16);
  ((uint4*)out)[i] = o;
}

// ---------------- kernel 2: transpose [R][C] f32 -> [C][R] bf16 ----------------
__global__ __launch_bounds__(256) void k_transpose(const float* __restrict__ in,
                                                   unsigned short* __restrict__ out,
                                                   int R, int C) {
  __shared__ float tile[64][65];
  int c0 = blockIdx.x * 64, r0 = blockIdx.y * 64;
  int tid = threadIdx.x;
  for (int i = tid; i < 4096; i += 256) {
    int r = i >> 6, c = i & 63;
    tile[r][c] = in[(size_t)(r0 + r) * C + c0 + c];
  }
  __syncthreads();
  for (int i = tid; i < 4096; i += 256) {
    int c = i >> 6, r = i & 63;
    out[(size_t)(c0 + c) * R + r0 + r] = f2bf(tile[r][c]);
  }
}

// ---------------- kernel 3: QKV GEMM  [8192][768] @ [768][2304] (+bias) ----------------
__global__ __launch_bounds__(256) void k_qkv(const unsigned short* __restrict__ A,
                                             const unsigned short* __restrict__ Bt,
                                             const float* __restrict__ bias,
                                             unsigned short* __restrict__ Qo,
                                             unsigned short* __restrict__ Ko,
                                             unsigned short* __restrict__ Vt) {
  __shared__ short As[128 * 64];
  __shared__ short Bs[128 * 64];
  const int tid = threadIdx.x;
  const int wave = tid >> 6, lane = tid & 63;
  const int wr = wave >> 1, wc = wave & 1;
  const int m0 = blockIdx.y * 128, n0 = blockIdx.x * 128;

  f32x4 acc[4][4] = {};

#pragma unroll 1
  for (int k0 = 0; k0 < 768; k0 += 64) {
#pragma unroll
    for (int it = 0; it < 4; ++it) {
      int chunk = wave * 4 + it;
      int slot = chunk * 64 + lane;
      int row = slot >> 3, j = slot & 7;
      int kcol = k0 + ((j ^ (row & 7)) << 3);
      gld_lds16(A  + (size_t)(m0 + row) * 768 + kcol, &As[chunk * 512]);
      gld_lds16(Bt + (size_t)(n0 + row) * 768 + kcol, &Bs[chunk * 512]);
    }
    __syncthreads();
#pragma unroll
    for (int kk = 0; kk < 2; ++kk) {
      bf16x8 af[4], bfr[4];
      int cbl = kk * 4 + (lane >> 4);
#pragma unroll
      for (int mi = 0; mi < 4; ++mi) {
        int row = wr * 64 + mi * 16 + (lane & 15);
        af[mi] = *(const bf16x8*)&As[(row * 8 + (cbl ^ (row & 7))) * 8];
      }
#pragma unroll
      for (int ni = 0; ni < 4; ++ni) {
        int row = wc * 64 + ni * 16 + (lane & 15);
        bfr[ni] = *(const bf16x8*)&Bs[(row * 8 + (cbl ^ (row & 7))) * 8];
      }
#pragma unroll
      for (int mi = 0; mi < 4; ++mi)
#pragma unroll
        for (int ni = 0; ni < 4; ++ni)
          acc[mi][ni] = __builtin_amdgcn_mfma_f32_16x16x32_bf16(af[mi], bfr[ni], acc[mi][ni], 0, 0, 0);
    }
    __syncthreads();
  }

  const int which = n0 / 768;
#pragma unroll
  for (int ni = 0; ni < 4; ++ni) {
    int col = n0 + wc * 64 + ni * 16 + (lane & 15);
    int nr = col - which * 768;
    int h = nr >> 6, d = nr & 63;
    float bi = bias[col];
#pragma unroll
    for (int mi = 0; mi < 4; ++mi) {
      int mt = m0 + wr * 64 + mi * 16 + ((lane >> 4) << 2);
      int b = mt >> 12, t = mt & 4095;
      size_t bh = (size_t)(b * NH + h);
#pragma unroll
      for (int r = 0; r < 4; ++r) {
        float v = acc[mi][ni][r] + bi;
        if (which == 0) {
          // Q pre-scaled by log2(e)/sqrt(64): QK^T emerges in log2 domain
          Qo[bh * (T_SEQ * HD) + (size_t)(t + r) * HD + d] = f2bf(v * 0.18033688011112042f);
        } else if (which == 1) {
          Ko[bh * (T_SEQ * HD) + (size_t)(t + r) * HD + d] = f2bf(v);
        } else {
          // Vt stored with key-column bits 2<->3 swapped (per 16-block permute) so that
          // contiguous b128 B-frag reads in k_attn deliver keys in the natural-P sigma order.
          int tc = t + r;
          int pc = (tc & ~12) | ((tc & 4) << 1) | ((tc & 8) >> 1);
          Vt[bh * (T_SEQ * HD) + (size_t)d * T_SEQ + pc] = f2bf(v);
        }
      }
    }
  }
}

// ---------------- kernel 4: flash attention, K-SPLIT=2 (swapped-QK^T, m=0, MFMA l-sum) ----------------
// grid (32 qtiles, 24 bh, 2 ksplit). 4 waves x 32 q-rows. KV tile = 64 keys, double-buffered.
// Each split handles 2048 keys and writes UNNORMALIZED partials Op (bf16) + row-sums Lp (f32);
// with m=0 softmax the merge is exactly additive: O = (O0+O1)/(l0+l1)  (k_combine).
__global__ __launch_bounds__(256, 4) void k_attn(const unsigned short* __restrict__ Q,
                                                 const unsigned short* __restrict__ K,
                                                 const unsigned short* __restrict__ Vt,
                                                 unsigned short* __restrict__ Op,
                                                 float* __restrict__ Lp) {
  __shared__ char ldsb[2][16384];   // [buf][ K tile 8 KiB | Vt tile 8 KiB ], XOR-swizzled
  const int tid = threadIdx.x, wave = tid >> 6, lane = tid & 63;
  const int hi = lane >> 5, l31 = lane & 31;
  const int qt = blockIdx.x, bh = blockIdx.y, ks = blockIdx.z;
  const int b = bh / NH, h = bh % NH;
  const size_t base = (size_t)bh * T_SEQ * HD;
  const int q0 = qt * 128 + wave * 32;

  // Q fragments (B-operand): col=q=l31, k(d) = 16t + 8*hi + j
  bf16x8 aq[4];
#pragma unroll
  for (int t = 0; t < 4; ++t)
    aq[t] = *(const bf16x8*)&Q[base + (size_t)(q0 + l31) * HD + t * 16 + hi * 8];

  // hoisted LDS byte offsets
  int koff[4];                              // K-frag: row l31 (+32*kb via +4096), chunk ((2t|hi)^(l31&7))
#pragma unroll
  for (int t = 0; t < 4; ++t)
    koff[t] = l31 * 128 + ((((t << 1) | hi) ^ (l31 & 7)) << 4);
  int voff[2][2];                           // V-frag: row l31 (+32*db via +4096), chunk ((4kb+2ks+hi)^(l31&7))
#pragma unroll
  for (int kb = 0; kb < 2; ++kb)
#pragma unroll
    for (int kss = 0; kss < 2; ++kss)
      voff[kb][kss] = ((((kb << 2) | (kss << 1) | hi) ^ (l31 & 7)) << 4) + l31 * 128;

  f32x16 oacc0 = {}, oacc1 = {}, lacc = {};
  union { unsigned u[4]; bf16x8 v; } onesf;   // all-1.0 bf16 B-frag for the l-sum MFMA
  onesf.u[0] = 0x3F803F80u; onesf.u[1] = 0x3F803F80u;
  onesf.u[2] = 0x3F803F80u; onesf.u[3] = 0x3F803F80u;

  auto STAGE = [&](int bufi, int k0) {
#pragma unroll
    for (int it = 0; it < 2; ++it) {
      int chunk = wave * 2 + it;
      int slot = chunk * 64 + lane;
      int row = slot >> 3, j = slot & 7;
      int ce = ((j ^ (row & 7)) << 3);       // pre-swizzled source column (elements)
      gld_lds16(K  + base + (size_t)(k0 + row) * HD + ce, ldsb[bufi] + chunk * 1024);
      gld_lds16(Vt + base + (size_t)row * T_SEQ + k0 + ce, ldsb[bufi] + 8192 + chunk * 1024);
    }
  };

  const int kt0 = ks * 32, ktEnd = kt0 + 32;
  STAGE(0, kt0 * 64);
  __syncthreads();

  int buf = 0;
#pragma unroll 1
  for (int kt = kt0; kt < ktEnd; ++kt) {
    if (kt + 1 < ktEnd) STAGE(buf ^ 1, (kt + 1) * 64);
    const char* Lq = ldsb[buf];
#pragma unroll
    for (int kb = 0; kb < 2; ++kb) {
      // ---- S^T = K_tile @ Q^T : s[key][q], col=q=l31, key=(r&3)+8*(r>>2)+4*hi (+32*kb)
      f32x16 s = {};
      const char* Kp = Lq + kb * 4096;
#pragma unroll
      for (int t = 0; t < 4; ++t) {
        bf16x8 kf = *(const bf16x8*)(Kp + koff[t]);
        s = __builtin_amdgcn_mfma_f32_32x32x16_bf16(kf, aq[t], s, 0, 0, 0);
      }
      // ---- P = exp2(S) via raw v_exp_f32 (Q pre-scaled; m=0 exact softmax)
#pragma unroll
      for (int r = 0; r < 16; ++r) s[r] = __builtin_amdgcn_exp2f(s[r]);
      // ---- pack P -> bf16 A-frags in NATURAL register order (no cross-lane moves).
      // Element (hi,j) of slice kss = key sigma_hi(j) = (j&3)+8*(j>>2)+4hi; the Vt column
      // permute (k_qkv) stores V so the b128 B-frag below has the SAME key order.
      unsigned w[8];
#pragma unroll
      for (int i = 0; i < 8; ++i) {
        unsigned wi;
        asm("v_cvt_pk_bf16_f32 %0, %1, %2" : "=v"(wi) : "v"(s[2 * i]), "v"(s[2 * i + 1]));
        w[i] = wi;
      }
      asm volatile("s_nop 2");   // VALU(asm)->MFMA wait states the hazard recognizer can't infer
      union { unsigned u[4]; bf16x8 v; } pf0, pf1;
      pf0.u[0] = w[0]; pf0.u[1] = w[1]; pf0.u[2] = w[2]; pf0.u[3] = w[3];   // slice kss=0
      pf1.u[0] = w[4]; pf1.u[1] = w[5]; pf1.u[2] = w[6]; pf1.u[3] = w[7];   // slice kss=1
      // ---- l += P @ ones ; O += P @ V   (matrix pipe; single b128 per (db,kss), conflict-free)
      const char* Vp = Lq + 8192;
      lacc = __builtin_amdgcn_mfma_f32_32x32x16_bf16(pf0.v, onesf.v, lacc, 0, 0, 0);
      lacc = __builtin_amdgcn_mfma_f32_32x32x16_bf16(pf1.v, onesf.v, lacc, 0, 0, 0);
#pragma unroll
      for (int kss = 0; kss < 2; ++kss) {
        bf16x8 v0 = *(const bf16x8*)(Vp + voff[kb][kss]);
        bf16x8 v1 = *(const bf16x8*)(Vp + 4096 + voff[kb][kss]);
        oacc0 = __builtin_amdgcn_mfma_f32_32x32x16_bf16(kss ? pf1.v : pf0.v, v0, oacc0, 0, 0, 0);
        oacc1 = __builtin_amdgcn_mfma_f32_32x32x16_bf16(kss ? pf1.v : pf0.v, v1, oacc1, 0, 0, 0);
      }
    }
    __syncthreads();
    buf ^= 1;
  }

  // epilogue: UNNORMALIZED partials. Op[ks][b*T+t][h*64+d] bf16; Lp[ks][bh][t] f32.
  unsigned short* OpS = Op + (size_t)ks * M_ROWS * CDIM;
  float* LpS = Lp + (size_t)ks * NBH * T_SEQ;
#pragma unroll
  for (int r = 0; r < 16; ++r) {
    int t = q0 + ((r & 3) + 8 * (r >> 2)) + 4 * hi;
    size_t rowb = (size_t)(b * T_SEQ + t) * CDIM + h * 64;
    OpS[rowb + l31]      = f2bf(oacc0[r]);
    OpS[rowb + 32 + l31] = f2bf(oacc1[r]);
    if (l31 == 0) LpS[(size_t)bh * T_SEQ + t] = lacc[r];
  }
}

// ---------------- kernel 4b: combine K-split partials  O = (O0+O1)/(l0+l1) ----------------
__global__ __launch_bounds__(256) void k_combine(const unsigned short* __restrict__ Op,
                                                 const float* __restrict__ Lp,
                                                 unsigned short* __restrict__ Ob) {
  int i = blockIdx.x * 256 + threadIdx.x;      // one 8-elem chunk; 8192*768/8/256 = 3072 blocks
  size_t e = (size_t)i * 8;
  int c = (int)(e % CDIM);
  int bt = (int)(e / CDIM);
  int t = bt & 4095, b = bt >> 12;
  int h = c >> 6;
  size_t li = (size_t)(b * NH + h) * T_SEQ + t;
  float inv = 1.0f / (Lp[li] + Lp[(size_t)NBH * T_SEQ + li]);
  uint4 p0 = ((const uint4*)Op)[i];
  uint4 p1 = ((const uint4*)(Op + (size_t)M_ROWS * CDIM))[i];
  unsigned pw0[4] = {p0.x, p0.y, p0.z, p0.w};
  unsigned pw1[4] = {p1.x, p1.y, p1.z, p1.w};
  unsigned ow[4];
#pragma unroll
  for (int k = 0; k < 4; ++k) {
    float a0 = __builtin_bit_cast(float, pw0[k] << 16);
    float a1 = __builtin_bit_cast(float, pw0[k] & 0xFFFF0000u);
    float b0 = __builtin_bit_cast(float, pw1[k] << 16);
    float b1 = __builtin_bit_cast(float, pw1[k] & 0xFFFF0000u);
    unsigned short lo = f2bf((a0 + b0) * inv);
    unsigned short hiw = f2bf((a1 + b1) * inv);
    ow[k] = (unsigned)lo | ((unsigned)hiw << 16);
  }
  uint4 o; o.x = ow[0]; o.y = ow[1]; o.z = ow[2]; o.w = ow[3];
  ((uint4*)Ob)[i] = o;
}

// ---------------- kernel 5: proj GEMM  [8192][768] @ [768][768] + bias -> f32 ----------------
__global__ __launch_bounds__(256) void k_proj(const unsigned short* __restrict__ A,
                                              const unsigned short* __restrict__ Bt,
                                              const float* __restrict__ bias,
                                              float* __restrict__ out) {
  __shared__ short As[128 * 64];
  __shared__ short Bs[128 * 64];
  const int tid = threadIdx.x;
  const int wave = tid >> 6, lane = tid & 63;
  const int wr = wave >> 1, wc = wave & 1;
  const int m0 = blockIdx.y * 128, n0 = blockIdx.x * 128;

  f32x4 acc[4][4] = {};

#pragma unroll 1
  for (int k0 = 0; k0 < 768; k0 += 64) {
#pragma unroll
    for (int it = 0; it < 4; ++it) {
      int chunk = wave * 4 + it;
      int slot = chunk * 64 + lane;
      int row = slot >> 3, j = slot & 7;
      int kcol = k0 + ((j ^ (row & 7)) << 3);
      gld_lds16(A  + (size_t)(m0 + row) * 768 + kcol, &As[chunk * 512]);
      gld_lds16(Bt + (size_t)(n0 + row) * 768 + kcol, &Bs[chunk * 512]);
    }
    __syncthreads();
#pragma unroll
    for (int kk = 0; kk < 2; ++kk) {
      bf16x8 af[4], bfr[4];
      int cbl = kk * 4 + (lane >> 4);
#pragma unroll
      for (int mi = 0; mi < 4; ++mi) {
        int row = wr * 64 + mi * 16 + (lane & 15);
        af[mi] = *(const bf16x8*)&As[(row * 8 + (cbl ^ (row & 7))) * 8];
      }
#pragma unroll
      for (int ni = 0; ni < 4; ++ni) {
        int row = wc * 64 + ni * 16 + (lane & 15);
        bfr[ni] = *(const bf16x8*)&Bs[(row * 8 + (cbl ^ (row & 7))) * 8];
      }
#pragma unroll
      for (int mi = 0; mi < 4; ++mi)
#pragma unroll
        for (int ni = 0; ni < 4; ++ni)
          acc[mi][ni] = __builtin_amdgcn_mfma_f32_16x16x32_bf16(af[mi], bfr[ni], acc[mi][ni], 0, 0, 0);
    }
    __syncthreads();
  }

#pragma unroll
  for (int ni = 0; ni < 4; ++ni) {
    int col = n0 + wc * 64 + ni * 16 + (lane & 15);
    float bi = bias[col];
#pragma unroll
    for (int mi = 0; mi < 4; ++mi) {
      int mt = m0 + wr * 64 + mi * 16 + ((lane >> 4) << 2);
#pragma unroll
      for (int r = 0; r < 4; ++r)
        out[(size_t)(mt + r) * CDIM + col] = acc[mi][ni][r] + bi;
    }
  }
}

extern "C" void kernel_launch(void* const* d_in, const int* in_sizes, int n_in,
                              void* d_out, int out_size, void* d_ws, size_t ws_size,
                              hipStream_t stream) {
  const float* x  = (const float*)d_in[0];
  const float* Wa = (const float*)d_in[1];
  const float* ba = (const float*)d_in[2];
  const float* Wp = (const float*)d_in[3];
  const float* bp = (const float*)d_in[4];

  char* ws = (char*)d_ws;
  unsigned short* xb  = (unsigned short*)(ws + OFF_XB);
  unsigned short* WaT = (unsigned short*)(ws + OFF_WAT);
  unsigned short* WpT = (unsigned short*)(ws + OFF_WPT);
  unsigned short* Qb  = (unsigned short*)(ws + OFF_Q);
  unsigned short* Kb  = (unsigned short*)(ws + OFF_K);
  unsigned short* Vtb = (unsigned short*)(ws + OFF_VT);
  unsigned short* Ob  = (unsigned short*)(ws + OFF_O);
  unsigned short* Opb = (unsigned short*)(ws + OFF_P);
  float*          Lpb = (float*)(ws + OFF_L);

  k_conv<<<3072, 256, 0, stream>>>(x, xb);
  k_transpose<<<dim3(36, 12), 256, 0, stream>>>(Wa, WaT, CDIM, 3 * CDIM);
  k_transpose<<<dim3(12, 12), 256, 0, stream>>>(Wp, WpT, CDIM, CDIM);
  k_qkv<<<dim3(18, 64), 256, 0, stream>>>(xb, WaT, ba, Qb, Kb, Vtb);
  k_attn<<<dim3(32, 24, 2), 256, 0, stream>>>(Qb, Kb, Vtb, Opb, Lpb);
  k_combine<<<3072, 256, 0, stream>>>(Opb, Lpb, Ob);
  k_proj<<<dim3(6, 64), 256, 0, stream>>>(Ob, WpT, bp, (float*)d_out);
}

// Round 15
// 229.503 us; speedup vs baseline: 1.0435x; 1.0435x over previous
//
#include <hip/hip_runtime.h>
#include <cstdint>
#include <cstddef>

#define DEV static __device__ __forceinline__

typedef __attribute__((ext_vector_type(8))) short bf16x8;
typedef __attribute__((ext_vector_type(4))) float f32x4;
typedef __attribute__((ext_vector_type(16))) float f32x16;

#define T_SEQ 4096
#define CDIM  768
#define NH    12
#define HD    64
#define NBH   24            // B * NH
#define M_ROWS 8192         // B * T

// ---- workspace layout (bytes) ----
#define OFF_XB   0ull
#define OFF_WAT  (OFF_XB  + (size_t)M_ROWS * CDIM * 2)       // xb: [8192][768] bf16
#define OFF_WPT  (OFF_WAT + (size_t)(3*CDIM) * CDIM * 2)     // WaT: [2304][768] bf16
#define OFF_Q    (OFF_WPT + (size_t)CDIM * CDIM * 2)         // WpT: [768][768] bf16
#define OFF_K    (OFF_Q   + (size_t)NBH * T_SEQ * HD * 2)    // Q: [24][4096][64] bf16 (pre-scaled by log2e/8)
#define OFF_VT   (OFF_K   + (size_t)NBH * T_SEQ * HD * 2)    // K: [24][4096][64] bf16
#define OFF_O    (OFF_VT  + (size_t)NBH * HD * T_SEQ * 2)    // Vt: [24][64][4096] bf16 (key cols bit2<->bit3 permuted)
// O: [8192][768] bf16

DEV unsigned short f2bf(float f) {            // RTNE f32 -> bf16
  unsigned u = __builtin_bit_cast(unsigned, f);
  u += 0x7FFFu + ((u >> 16) & 1u);
  return (unsigned short)(u >> 16);
}

DEV void gld_lds16(const void* g, void* l) {  // async global->LDS, 16B/lane, dest = wave-uniform base + lane*16
  __builtin_amdgcn_global_load_lds(
      (const __attribute__((address_space(1))) void*)g,
      (__attribute__((address_space(3))) void*)l, 16, 0, 0);
}

// Atomic 8x cvt_pk blob: all cvts contiguous (no MFMA can be scheduled between them)
// + s_nop 3 tail so every output has >=4 wait states before any consuming MFMA.
// Early-clobber outputs prevent input/output register aliasing within the blob.
DEV void cvt8(const f32x16& s, unsigned* w) {
  asm("v_cvt_pk_bf16_f32 %0, %8, %9\n\t"
      "v_cvt_pk_bf16_f32 %1, %10, %11\n\t"
      "v_cvt_pk_bf16_f32 %2, %12, %13\n\t"
      "v_cvt_pk_bf16_f32 %3, %14, %15\n\t"
      "v_cvt_pk_bf16_f32 %4, %16, %17\n\t"
      "v_cvt_pk_bf16_f32 %5, %18, %19\n\t"
      "v_cvt_pk_bf16_f32 %6, %20, %21\n\t"
      "v_cvt_pk_bf16_f32 %7, %22, %23\n\t"
      "s_nop 3"
      : "=&v"(w[0]), "=&v"(w[1]), "=&v"(w[2]), "=&v"(w[3]),
        "=&v"(w[4]), "=&v"(w[5]), "=&v"(w[6]), "=&v"(w[7])
      : "v"(s[0]), "v"(s[1]), "v"(s[2]), "v"(s[3]),
        "v"(s[4]), "v"(s[5]), "v"(s[6]), "v"(s[7]),
        "v"(s[8]), "v"(s[9]), "v"(s[10]), "v"(s[11]),
        "v"(s[12]), "v"(s[13]), "v"(s[14]), "v"(s[15]));
}

// ---------------- kernel 1: cast x f32 -> bf16 ----------------
__global__ __launch_bounds__(256) void k_conv(const float* __restrict__ in,
                                              unsigned short* __restrict__ out) {
  int i = blockIdx.x * 256 + threadIdx.x;
  const float4* p = (const float4*)in;
  float4 a = p[i * 2], b = p[i * 2 + 1];
  uint4 o;
  o.x = (unsigned)f2bf(a.x) | ((unsigned)f2bf(a.y) << 16);
  o.y = (unsigned)f2bf(a.z) | ((unsigned)f2bf(a.w) << 16);
  o.z = (unsigned)f2bf(b.x) | ((unsigned)f2bf(b.y) << 16);
  o.w = (unsigned)f2bf(b.z) | ((unsigned)f2bf(b.w) << 16);
  ((uint4*)out)[i] = o;
}

// ---------------- kernel 2: transpose [R][C] f32 -> [C][R] bf16 ----------------
__global__ __launch_bounds__(256) void k_transpose(const float* __restrict__ in,
                                                   unsigned short* __restrict__ out,
                                                   int R, int C) {
  __shared__ float tile[64][65];
  int c0 = blockIdx.x * 64, r0 = blockIdx.y * 64;
  int tid = threadIdx.x;
  for (int i = tid; i < 4096; i += 256) {
    int r = i >> 6, c = i & 63;
    tile[r][c] = in[(size_t)(r0 + r) * C + c0 + c];
  }
  __syncthreads();
  for (int i = tid; i < 4096; i += 256) {
    int c = i >> 6, r = i & 63;
    out[(size_t)(c0 + c) * R + r0 + r] = f2bf(tile[r][c]);
  }
}

// ---------------- kernel 3: QKV GEMM  [8192][768] @ [768][2304] (+bias) ----------------
__global__ __launch_bounds__(256) void k_qkv(const unsigned short* __restrict__ A,
                                             const unsigned short* __restrict__ Bt,
                                             const float* __restrict__ bias,
                                             unsigned short* __restrict__ Qo,
                                             unsigned short* __restrict__ Ko,
                                             unsigned short* __restrict__ Vt) {
  __shared__ short As[128 * 64];
  __shared__ short Bs[128 * 64];
  const int tid = threadIdx.x;
  const int wave = tid >> 6, lane = tid & 63;
  const int wr = wave >> 1, wc = wave & 1;
  const int m0 = blockIdx.y * 128, n0 = blockIdx.x * 128;

  f32x4 acc[4][4] = {};

#pragma unroll 1
  for (int k0 = 0; k0 < 768; k0 += 64) {
#pragma unroll
    for (int it = 0; it < 4; ++it) {
      int chunk = wave * 4 + it;
      int slot = chunk * 64 + lane;
      int row = slot >> 3, j = slot & 7;
      int kcol = k0 + ((j ^ (row & 7)) << 3);
      gld_lds16(A  + (size_t)(m0 + row) * 768 + kcol, &As[chunk * 512]);
      gld_lds16(Bt + (size_t)(n0 + row) * 768 + kcol, &Bs[chunk * 512]);
    }
    __syncthreads();
#pragma unroll
    for (int kk = 0; kk < 2; ++kk) {
      bf16x8 af[4], bfr[4];
      int cbl = kk * 4 + (lane >> 4);
#pragma unroll
      for (int mi = 0; mi < 4; ++mi) {
        int row = wr * 64 + mi * 16 + (lane & 15);
        af[mi] = *(const bf16x8*)&As[(row * 8 + (cbl ^ (row & 7))) * 8];
      }
#pragma unroll
      for (int ni = 0; ni < 4; ++ni) {
        int row = wc * 64 + ni * 16 + (lane & 15);
        bfr[ni] = *(const bf16x8*)&Bs[(row * 8 + (cbl ^ (row & 7))) * 8];
      }
#pragma unroll
      for (int mi = 0; mi < 4; ++mi)
#pragma unroll
        for (int ni = 0; ni < 4; ++ni)
          acc[mi][ni] = __builtin_amdgcn_mfma_f32_16x16x32_bf16(af[mi], bfr[ni], acc[mi][ni], 0, 0, 0);
    }
    __syncthreads();
  }

  const int which = n0 / 768;
#pragma unroll
  for (int ni = 0; ni < 4; ++ni) {
    int col = n0 + wc * 64 + ni * 16 + (lane & 15);
    int nr = col - which * 768;
    int h = nr >> 6, d = nr & 63;
    float bi = bias[col];
#pragma unroll
    for (int mi = 0; mi < 4; ++mi) {
      int mt = m0 + wr * 64 + mi * 16 + ((lane >> 4) << 2);
      int b = mt >> 12, t = mt & 4095;
      size_t bh = (size_t)(b * NH + h);
#pragma unroll
      for (int r = 0; r < 4; ++r) {
        float v = acc[mi][ni][r] + bi;
        if (which == 0) {
          // Q pre-scaled by log2(e)/sqrt(64): QK^T emerges in log2 domain
          Qo[bh * (T_SEQ * HD) + (size_t)(t + r) * HD + d] = f2bf(v * 0.18033688011112042f);
        } else if (which == 1) {
          Ko[bh * (T_SEQ * HD) + (size_t)(t + r) * HD + d] = f2bf(v);
        } else {
          // Vt stored with key-column bits 2<->3 swapped (per 16-block permute) so that
          // contiguous b128 B-frag reads in k_attn deliver keys in the natural-P sigma order.
          int tc = t + r;
          int pc = (tc & ~12) | ((tc & 4) << 1) | ((tc & 8) >> 1);
          Vt[bh * (T_SEQ * HD) + (size_t)d * T_SEQ + pc] = f2bf(v);
        }
      }
    }
  }
}

// ---------------- kernel 4: flash attention (swapped-QK^T, m=0, MFMA l-sum, phase-overlapped) ----------------
// grid (32 qtiles, 24 bh). 4 waves x 32 q-rows. KV tile = 64 keys, double-buffered.
// Phase-offset order: QK0 -> cvt0 -> QK1 -> PV0 || exp2/cvt1 -> PV1. The cvt8 blob is
// atomic (no MFMA can interleave between cvts) and carries its own s_nop tail, making
// the VALU(asm)->MFMA spacing deterministic regardless of scheduling.
__global__ __launch_bounds__(256, 3) void k_attn(const unsigned short* __restrict__ Q,
                                                 const unsigned short* __restrict__ K,
                                                 const unsigned short* __restrict__ Vt,
                                                 unsigned short* __restrict__ O) {
  __shared__ char ldsb[2][16384];   // [buf][ K tile 8 KiB | Vt tile 8 KiB ], XOR-swizzled
  const int tid = threadIdx.x, wave = tid >> 6, lane = tid & 63;
  const int hi = lane >> 5, l31 = lane & 31;
  const int qt = blockIdx.x, bh = blockIdx.y;
  const int b = bh / NH, h = bh % NH;
  const size_t base = (size_t)bh * T_SEQ * HD;
  const int q0 = qt * 128 + wave * 32;

  // Q fragments (B-operand): col=q=l31, k(d) = 16t + 8*hi + j
  bf16x8 aq[4];
#pragma unroll
  for (int t = 0; t < 4; ++t)
    aq[t] = *(const bf16x8*)&Q[base + (size_t)(q0 + l31) * HD + t * 16 + hi * 8];

  // hoisted LDS byte offsets
  int koff[4];                              // K-frag: row l31 (+32*kb via +4096), chunk ((2t|hi)^(l31&7))
#pragma unroll
  for (int t = 0; t < 4; ++t)
    koff[t] = l31 * 128 + ((((t << 1) | hi) ^ (l31 & 7)) << 4);
  int voff[2][2];                           // V-frag: row l31 (+32*db via +4096), chunk ((4kb+2ks+hi)^(l31&7))
#pragma unroll
  for (int kb = 0; kb < 2; ++kb)
#pragma unroll
    for (int ks = 0; ks < 2; ++ks)
      voff[kb][ks] = ((((kb << 2) | (ks << 1) | hi) ^ (l31 & 7)) << 4) + l31 * 128;

  f32x16 oacc0 = {}, oacc1 = {}, lacc = {};
  union { unsigned u[4]; bf16x8 v; } onesf;   // all-1.0 bf16 B-frag for the l-sum MFMA
  onesf.u[0] = 0x3F803F80u; onesf.u[1] = 0x3F803F80u;
  onesf.u[2] = 0x3F803F80u; onesf.u[3] = 0x3F803F80u;

  auto STAGE = [&](int bufi, int k0) {
#pragma unroll
    for (int it = 0; it < 2; ++it) {
      int chunk = wave * 2 + it;
      int slot = chunk * 64 + lane;
      int row = slot >> 3, j = slot & 7;
      int ce = ((j ^ (row & 7)) << 3);       // pre-swizzled source column (elements)
      gld_lds16(K  + base + (size_t)(k0 + row) * HD + ce, ldsb[bufi] + chunk * 1024);
      gld_lds16(Vt + base + (size_t)row * T_SEQ + k0 + ce, ldsb[bufi] + 8192 + chunk * 1024);
    }
  };

  STAGE(0, 0);
  __syncthreads();

  int buf = 0;
#pragma unroll 1
  for (int kt = 0; kt < 64; ++kt) {
    if (kt < 63) STAGE(buf ^ 1, (kt + 1) * 64);
    const char* Lp = ldsb[buf];
    const char* Vp = Lp + 8192;

    // ---- QK0: S^T half 0 (keys kb=0)
    f32x16 s0 = {};
#pragma unroll
    for (int t = 0; t < 4; ++t) {
      bf16x8 kf = *(const bf16x8*)(Lp + koff[t]);
      s0 = __builtin_amdgcn_mfma_f32_32x32x16_bf16(kf, aq[t], s0, 0, 0, 0);
    }
    // ---- exp2/cvt 0 (atomic blob)
#pragma unroll
    for (int r = 0; r < 16; ++r) s0[r] = __builtin_amdgcn_exp2f(s0[r]);
    unsigned w0[8];
    cvt8(s0, w0);
    union { unsigned u[4]; bf16x8 v; } pf00, pf01;
    pf00.u[0] = w0[0]; pf00.u[1] = w0[1]; pf00.u[2] = w0[2]; pf00.u[3] = w0[3];
    pf01.u[0] = w0[4]; pf01.u[1] = w0[5]; pf01.u[2] = w0[6]; pf01.u[3] = w0[7];

    // ---- QK1: S^T half 1 (keys kb=1) — matrix pipe
    f32x16 s1 = {};
#pragma unroll
    for (int t = 0; t < 4; ++t) {
      bf16x8 kf = *(const bf16x8*)(Lp + 4096 + koff[t]);
      s1 = __builtin_amdgcn_mfma_f32_32x32x16_bf16(kf, aq[t], s1, 0, 0, 0);
    }

    // ---- PV0 + l0 (matrix pipe) — overlaps exp2/cvt 1 below (no data deps)
    lacc = __builtin_amdgcn_mfma_f32_32x32x16_bf16(pf00.v, onesf.v, lacc, 0, 0, 0);
    lacc = __builtin_amdgcn_mfma_f32_32x32x16_bf16(pf01.v, onesf.v, lacc, 0, 0, 0);
    {
      bf16x8 v0 = *(const bf16x8*)(Vp + voff[0][0]);
      bf16x8 v1 = *(const bf16x8*)(Vp + voff[0][1]);
      bf16x8 u0 = *(const bf16x8*)(Vp + 4096 + voff[0][0]);
      bf16x8 u1 = *(const bf16x8*)(Vp + 4096 + voff[0][1]);
      oacc0 = __builtin_amdgcn_mfma_f32_32x32x16_bf16(pf00.v, v0, oacc0, 0, 0, 0);
      oacc0 = __builtin_amdgcn_mfma_f32_32x32x16_bf16(pf01.v, v1, oacc0, 0, 0, 0);
      oacc1 = __builtin_amdgcn_mfma_f32_32x32x16_bf16(pf00.v, u0, oacc1, 0, 0, 0);
      oacc1 = __builtin_amdgcn_mfma_f32_32x32x16_bf16(pf01.v, u1, oacc1, 0, 0, 0);
    }

    // ---- exp2/cvt 1 (VALU/trans pipe — schedulable against PV0)
#pragma unroll
    for (int r = 0; r < 16; ++r) s1[r] = __builtin_amdgcn_exp2f(s1[r]);
    unsigned w1[8];
    cvt8(s1, w1);
    union { unsigned u[4]; bf16x8 v; } pf10, pf11;
    pf10.u[0] = w1[0]; pf10.u[1] = w1[1]; pf10.u[2] = w1[2]; pf10.u[3] = w1[3];
    pf11.u[0] = w1[4]; pf11.u[1] = w1[5]; pf11.u[2] = w1[6]; pf11.u[3] = w1[7];

    // ---- PV1 + l1
    lacc = __builtin_amdgcn_mfma_f32_32x32x16_bf16(pf10.v, onesf.v, lacc, 0, 0, 0);
    lacc = __builtin_amdgcn_mfma_f32_32x32x16_bf16(pf11.v, onesf.v, lacc, 0, 0, 0);
    {
      bf16x8 v0 = *(const bf16x8*)(Vp + voff[1][0]);
      bf16x8 v1 = *(const bf16x8*)(Vp + voff[1][1]);
      bf16x8 u0 = *(const bf16x8*)(Vp + 4096 + voff[1][0]);
      bf16x8 u1 = *(const bf16x8*)(Vp + 4096 + voff[1][1]);
      oacc0 = __builtin_amdgcn_mfma_f32_32x32x16_bf16(pf10.v, v0, oacc0, 0, 0, 0);
      oacc0 = __builtin_amdgcn_mfma_f32_32x32x16_bf16(pf11.v, v1, oacc0, 0, 0, 0);
      oacc1 = __builtin_amdgcn_mfma_f32_32x32x16_bf16(pf10.v, u0, oacc1, 0, 0, 0);
      oacc1 = __builtin_amdgcn_mfma_f32_32x32x16_bf16(pf11.v, u1, oacc1, 0, 0, 0);
    }

    __syncthreads();
    buf ^= 1;
  }

  // epilogue: O[b][t][h*64+d], d = db*32 + l31; lacc[r] already holds l for row crow(r,hi)
#pragma unroll
  for (int r = 0; r < 16; ++r) {
    float inv = 1.0f / lacc[r];
    int t = q0 + ((r & 3) + 8 * (r >> 2)) + 4 * hi;
    size_t rowb = (size_t)(b * T_SEQ + t) * CDIM + h * 64;
    O[rowb + l31]      = f2bf(oacc0[r] * inv);
    O[rowb + 32 + l31] = f2bf(oacc1[r] * inv);
  }
}

// ---------------- kernel 5: proj GEMM  [8192][768] @ [768][768] + bias -> f32 ----------------
__global__ __launch_bounds__(256) void k_proj(const unsigned short* __restrict__ A,
                                              const unsigned short* __restrict__ Bt,
                                              const float* __restrict__ bias,
                                              float* __restrict__ out) {
  __shared__ short As[128 * 64];
  __shared__ short Bs[128 * 64];
  const int tid = threadIdx.x;
  const int wave = tid >> 6, lane = tid & 63;
  const int wr = wave >> 1, wc = wave & 1;
  const int m0 = blockIdx.y * 128, n0 = blockIdx.x * 128;

  f32x4 acc[4][4] = {};

#pragma unroll 1
  for (int k0 = 0; k0 < 768; k0 += 64) {
#pragma unroll
    for (int it = 0; it < 4; ++it) {
      int chunk = wave * 4 + it;
      int slot = chunk * 64 + lane;
      int row = slot >> 3, j = slot & 7;
      int kcol = k0 + ((j ^ (row & 7)) << 3);
      gld_lds16(A  + (size_t)(m0 + row) * 768 + kcol, &As[chunk * 512]);
      gld_lds16(Bt + (size_t)(n0 + row) * 768 + kcol, &Bs[chunk * 512]);
    }
    __syncthreads();
#pragma unroll
    for (int kk = 0; kk < 2; ++kk) {
      bf16x8 af[4], bfr[4];
      int cbl = kk * 4 + (lane >> 4);
#pragma unroll
      for (int mi = 0; mi < 4; ++mi) {
        int row = wr * 64 + mi * 16 + (lane & 15);
        af[mi] = *(const bf16x8*)&As[(row * 8 + (cbl ^ (row & 7))) * 8];
      }
#pragma unroll
      for (int ni = 0; ni < 4; ++ni) {
        int row = wc * 64 + ni * 16 + (lane & 15);
        bfr[ni] = *(const bf16x8*)&Bs[(row * 8 + (cbl ^ (row & 7))) * 8];
      }
#pragma unroll
      for (int mi = 0; mi < 4; ++mi)
#pragma unroll
        for (int ni = 0; ni < 4; ++ni)
          acc[mi][ni] = __builtin_amdgcn_mfma_f32_16x16x32_bf16(af[mi], bfr[ni], acc[mi][ni], 0, 0, 0);
    }
    __syncthreads();
  }

#pragma unroll
  for (int ni = 0; ni < 4; ++ni) {
    int col = n0 + wc * 64 + ni * 16 + (lane & 15);
    float bi = bias[col];
#pragma unroll
    for (int mi = 0; mi < 4; ++mi) {
      int mt = m0 + wr * 64 + mi * 16 + ((lane >> 4) << 2);
#pragma unroll
      for (int r = 0; r < 4; ++r)
        out[(size_t)(mt + r) * CDIM + col] = acc[mi][ni][r] + bi;
    }
  }
}

extern "C" void kernel_launch(void* const* d_in, const int* in_sizes, int n_in,
                              void* d_out, int out_size, void* d_ws, size_t ws_size,
                              hipStream_t stream) {
  const float* x  = (const float*)d_in[0];
  const float* Wa = (const float*)d_in[1];
  const float* ba = (const float*)d_in[2];
  const float* Wp = (const float*)d_in[3];
  const float* bp = (const float*)d_in[4];

  char* ws = (char*)d_ws;
  unsigned short* xb  = (unsigned short*)(ws + OFF_XB);
  unsigned short* WaT = (unsigned short*)(ws + OFF_WAT);
  unsigned short* WpT = (unsigned short*)(ws + OFF_WPT);
  unsigned short* Qb  = (unsigned short*)(ws + OFF_Q);
  unsigned short* Kb  = (unsigned short*)(ws + OFF_K);
  unsigned short* Vtb = (unsigned short*)(ws + OFF_VT);
  unsigned short* Ob  = (unsigned short*)(ws + OFF_O);

  k_conv<<<3072, 256, 0, stream>>>(x, xb);
  k_transpose<<<dim3(36, 12), 256, 0, stream>>>(Wa, WaT, CDIM, 3 * CDIM);
  k_transpose<<<dim3(12, 12), 256, 0, stream>>>(Wp, WpT, CDIM, CDIM);
  k_qkv<<<dim3(18, 64), 256, 0, stream>>>(xb, WaT, ba, Qb, Kb, Vtb);
  k_attn<<<dim3(32, 24), 256, 0, stream>>>(Qb, Kb, Vtb, Ob);
  k_proj<<<dim3(6, 64), 256, 0, stream>>>(Ob, WpT, bp, (float*)d_out);
}

// Round 17
// 222.861 us; speedup vs baseline: 1.0746x; 1.0298x over previous
//
#include <hip/hip_runtime.h>
#include <cstdint>
#include <cstddef>

#define DEV static __device__ __forceinline__

typedef __attribute__((ext_vector_type(8))) short bf16x8;
typedef __attribute__((ext_vector_type(4))) float f32x4;
typedef __attribute__((ext_vector_type(16))) float f32x16;

#define T_SEQ 4096
#define CDIM  768
#define NH    12
#define HD    64
#define NBH   24            // B * NH
#define M_ROWS 8192         // B * T

// ---- workspace layout (bytes) ----
#define OFF_XB   0ull
#define OFF_WAT  (OFF_XB  + (size_t)M_ROWS * CDIM * 2)       // xb: [8192][768] bf16
#define OFF_WPT  (OFF_WAT + (size_t)(3*CDIM) * CDIM * 2)     // WaT: [2304][768] bf16
#define OFF_Q    (OFF_WPT + (size_t)CDIM * CDIM * 2)         // WpT: [768][768] bf16
#define OFF_K    (OFF_Q   + (size_t)NBH * T_SEQ * HD * 2)    // Q: [24][4096][64] bf16 (pre-scaled by log2e/8)
#define OFF_VT   (OFF_K   + (size_t)NBH * T_SEQ * HD * 2)    // K: [24][4096][64] bf16
#define OFF_O    (OFF_VT  + (size_t)NBH * HD * T_SEQ * 2)    // Vt: [24][64][4096] bf16 (key cols bit2<->bit3 permuted)
// O: [8192][768] bf16

DEV unsigned short f2bf(float f) {            // RTNE f32 -> bf16
  unsigned u = __builtin_bit_cast(unsigned, f);
  u += 0x7FFFu + ((u >> 16) & 1u);
  return (unsigned short)(u >> 16);
}

DEV void gld_lds16(const void* g, void* l) {  // async global->LDS, 16B/lane, dest = wave-uniform base + lane*16
  __builtin_amdgcn_global_load_lds(
      (const __attribute__((address_space(1))) void*)g,
      (__attribute__((address_space(3))) void*)l, 16, 0, 0);
}

// Atomic 8x cvt_pk blob: all cvts contiguous (no MFMA can be scheduled between them)
// + s_nop 3 tail so every output has >=4 wait states before any consuming MFMA.
DEV void cvt8(const f32x16& s, unsigned* w) {
  asm("v_cvt_pk_bf16_f32 %0, %8, %9\n\t"
      "v_cvt_pk_bf16_f32 %1, %10, %11\n\t"
      "v_cvt_pk_bf16_f32 %2, %12, %13\n\t"
      "v_cvt_pk_bf16_f32 %3, %14, %15\n\t"
      "v_cvt_pk_bf16_f32 %4, %16, %17\n\t"
      "v_cvt_pk_bf16_f32 %5, %18, %19\n\t"
      "v_cvt_pk_bf16_f32 %6, %20, %21\n\t"
      "v_cvt_pk_bf16_f32 %7, %22, %23\n\t"
      "s_nop 3"
      : "=&v"(w[0]), "=&v"(w[1]), "=&v"(w[2]), "=&v"(w[3]),
        "=&v"(w[4]), "=&v"(w[5]), "=&v"(w[6]), "=&v"(w[7])
      : "v"(s[0]), "v"(s[1]), "v"(s[2]), "v"(s[3]),
        "v"(s[4]), "v"(s[5]), "v"(s[6]), "v"(s[7]),
        "v"(s[8]), "v"(s[9]), "v"(s[10]), "v"(s[11]),
        "v"(s[12]), "v"(s[13]), "v"(s[14]), "v"(s[15]));
}

// ---------------- kernel 1: cast x f32 -> bf16 ----------------
__global__ __launch_bounds__(256) void k_conv(const float* __restrict__ in,
                                              unsigned short* __restrict__ out) {
  int i = blockIdx.x * 256 + threadIdx.x;
  const float4* p = (const float4*)in;
  float4 a = p[i * 2], b = p[i * 2 + 1];
  uint4 o;
  o.x = (unsigned)f2bf(a.x) | ((unsigned)f2bf(a.y) << 16);
  o.y = (unsigned)f2bf(a.z) | ((unsigned)f2bf(a.w) << 16);
  o.z = (unsigned)f2bf(b.x) | ((unsigned)f2bf(b.y) << 16);
  o.w = (unsigned)f2bf(b.z) | ((unsigned)f2bf(b.w) << 16);
  ((uint4*)out)[i] = o;
}

// ---------------- kernel 2: transpose [R][C] f32 -> [C][R] bf16 ----------------
__global__ __launch_bounds__(256) void k_transpose(const float* __restrict__ in,
                                                   unsigned short* __restrict__ out,
                                                   int R, int C) {
  __shared__ float tile[64][65];
  int c0 = blockIdx.x * 64, r0 = blockIdx.y * 64;
  int tid = threadIdx.x;
  for (int i = tid; i < 4096; i += 256) {
    int r = i >> 6, c = i & 63;
    tile[r][c] = in[(size_t)(r0 + r) * C + c0 + c];
  }
  __syncthreads();
  for (int i = tid; i < 4096; i += 256) {
    int c = i >> 6, r = i & 63;
    out[(size_t)(c0 + c) * R + r0 + r] = f2bf(tile[r][c]);
  }
}

// ---------------- kernel 3: QKV GEMM  [8192][768] @ [768][2304] (+bias) ----------------
__global__ __launch_bounds__(256) void k_qkv(const unsigned short* __restrict__ A,
                                             const unsigned short* __restrict__ Bt,
                                             const float* __restrict__ bias,
                                             unsigned short* __restrict__ Qo,
                                             unsigned short* __restrict__ Ko,
                                             unsigned short* __restrict__ Vt) {
  __shared__ short As[128 * 64];
  __shared__ short Bs[128 * 64];
  const int tid = threadIdx.x;
  const int wave = tid >> 6, lane = tid & 63;
  const int wr = wave >> 1, wc = wave & 1;
  // XCD-aware swizzle (m204, 1152 = 8*144): each XCD gets 8 contiguous m-rows -> B L2-resident
  const int lin = blockIdx.y * 18 + blockIdx.x;
  const int wg = (lin & 7) * 144 + (lin >> 3);
  const int m0 = (wg / 18) * 128, n0 = (wg % 18) * 128;

  f32x4 acc[4][4] = {};

#pragma unroll 1
  for (int k0 = 0; k0 < 768; k0 += 64) {
#pragma unroll
    for (int it = 0; it < 4; ++it) {
      int chunk = wave * 4 + it;
      int slot = chunk * 64 + lane;
      int row = slot >> 3, j = slot & 7;
      int kcol = k0 + ((j ^ (row & 7)) << 3);
      gld_lds16(A  + (size_t)(m0 + row) * 768 + kcol, &As[chunk * 512]);
      gld_lds16(Bt + (size_t)(n0 + row) * 768 + kcol, &Bs[chunk * 512]);
    }
    __syncthreads();
#pragma unroll
    for (int kk = 0; kk < 2; ++kk) {
      bf16x8 af[4], bfr[4];
      int cbl = kk * 4 + (lane >> 4);
#pragma unroll
      for (int mi = 0; mi < 4; ++mi) {
        int row = wr * 64 + mi * 16 + (lane & 15);
        af[mi] = *(const bf16x8*)&As[(row * 8 + (cbl ^ (row & 7))) * 8];
      }
#pragma unroll
      for (int ni = 0; ni < 4; ++ni) {
        int row = wc * 64 + ni * 16 + (lane & 15);
        bfr[ni] = *(const bf16x8*)&Bs[(row * 8 + (cbl ^ (row & 7))) * 8];
      }
#pragma unroll
      for (int mi = 0; mi < 4; ++mi)
#pragma unroll
        for (int ni = 0; ni < 4; ++ni)
          acc[mi][ni] = __builtin_amdgcn_mfma_f32_16x16x32_bf16(af[mi], bfr[ni], acc[mi][ni], 0, 0, 0);
    }
    __syncthreads();
  }

  const int which = n0 / 768;
#pragma unroll
  for (int ni = 0; ni < 4; ++ni) {
    int col = n0 + wc * 64 + ni * 16 + (lane & 15);
    int nr = col - which * 768;
    int h = nr >> 6, d = nr & 63;
    float bi = bias[col];
#pragma unroll
    for (int mi = 0; mi < 4; ++mi) {
      int mt = m0 + wr * 64 + mi * 16 + ((lane >> 4) << 2);
      int b = mt >> 12, t = mt & 4095;
      size_t bh = (size_t)(b * NH + h);
#pragma unroll
      for (int r = 0; r < 4; ++r) {
        float v = acc[mi][ni][r] + bi;
        if (which == 0) {
          // Q pre-scaled by log2(e)/sqrt(64): QK^T emerges in log2 domain
          Qo[bh * (T_SEQ * HD) + (size_t)(t + r) * HD + d] = f2bf(v * 0.18033688011112042f);
        } else if (which == 1) {
          Ko[bh * (T_SEQ * HD) + (size_t)(t + r) * HD + d] = f2bf(v);
        } else {
          // Vt stored with key-column bits 2<->3 swapped (per 16-block permute) so that
          // contiguous b128 B-frag reads in k_attn deliver keys in the natural-P sigma order.
          int tc = t + r;
          int pc = (tc & ~12) | ((tc & 4) << 1) | ((tc & 8) >> 1);
          Vt[bh * (T_SEQ * HD) + (size_t)d * T_SEQ + pc] = f2bf(v);
        }
      }
    }
  }
}

// ---------------- kernel 4: flash attention (swapped-QK^T, m=0, VALU l-sum, XCD swizzle) ----------------
// grid (32 qtiles, 24 bh) remapped so each XCD owns 3 bh (K/V 3MB -> L2-resident).
// 4 waves x 32 q-rows. KV tile = 64 keys, double-buffered. l-sum on VALU tree
// (matrix pipe leads at ~49%; VALU at ~39% has headroom).
__global__ __launch_bounds__(256, 3) void k_attn(const unsigned short* __restrict__ Q,
                                                 const unsigned short* __restrict__ K,
                                                 const unsigned short* __restrict__ Vt,
                                                 unsigned short* __restrict__ O) {
  __shared__ char ldsb[2][16384];   // [buf][ K tile 8 KiB | Vt tile 8 KiB ], XOR-swizzled
  const int tid = threadIdx.x, wave = tid >> 6, lane = tid & 63;
  const int hi = lane >> 5, l31 = lane & 31;
  // XCD-aware swizzle (m204, 768 = 8*96): XCD x owns wg [x*96,(x+1)*96) = bh [3x,3x+3)
  const int lin = blockIdx.y * 32 + blockIdx.x;
  const int wg = (lin & 7) * 96 + (lin >> 3);
  const int qt = wg & 31, bh = wg >> 5;
  const int b = bh / NH, h = bh % NH;
  const size_t base = (size_t)bh * T_SEQ * HD;
  const int q0 = qt * 128 + wave * 32;

  // Q fragments (B-operand): col=q=l31, k(d) = 16t + 8*hi + j
  bf16x8 aq[4];
#pragma unroll
  for (int t = 0; t < 4; ++t)
    aq[t] = *(const bf16x8*)&Q[base + (size_t)(q0 + l31) * HD + t * 16 + hi * 8];

  // hoisted LDS byte offsets
  int koff[4];                              // K-frag: row l31 (+32*kb via +4096), chunk ((2t|hi)^(l31&7))
#pragma unroll
  for (int t = 0; t < 4; ++t)
    koff[t] = l31 * 128 + ((((t << 1) | hi) ^ (l31 & 7)) << 4);
  int voff[2][2];                           // V-frag: row l31 (+32*db via +4096), chunk ((4kb+2ks+hi)^(l31&7))
#pragma unroll
  for (int kb = 0; kb < 2; ++kb)
#pragma unroll
    for (int ks = 0; ks < 2; ++ks)
      voff[kb][ks] = ((((kb << 2) | (ks << 1) | hi) ^ (l31 & 7)) << 4) + l31 * 128;

  f32x16 oacc0 = {}, oacc1 = {};
  float l = 0.f;    // per-lane partial: sum over this half's keys for q-row l31

  auto STAGE = [&](int bufi, int k0) {
#pragma unroll
    for (int it = 0; it < 2; ++it) {
      int chunk = wave * 2 + it;
      int slot = chunk * 64 + lane;
      int row = slot >> 3, j = slot & 7;
      int ce = ((j ^ (row & 7)) << 3);       // pre-swizzled source column (elements)
      gld_lds16(K  + base + (size_t)(k0 + row) * HD + ce, ldsb[bufi] + chunk * 1024);
      gld_lds16(Vt + base + (size_t)row * T_SEQ + k0 + ce, ldsb[bufi] + 8192 + chunk * 1024);
    }
  };

  STAGE(0, 0);
  __syncthreads();

  int buf = 0;
#pragma unroll 1
  for (int kt = 0; kt < 64; ++kt) {
    if (kt < 63) STAGE(buf ^ 1, (kt + 1) * 64);
    const char* Lp = ldsb[buf];
    const char* Vp = Lp + 8192;

    // ---- QK0: S^T half 0 (keys kb=0)
    f32x16 s0 = {};
#pragma unroll
    for (int t = 0; t < 4; ++t) {
      bf16x8 kf = *(const bf16x8*)(Lp + koff[t]);
      s0 = __builtin_amdgcn_mfma_f32_32x32x16_bf16(kf, aq[t], s0, 0, 0, 0);
    }
    // ---- exp2 + l-tree + cvt 0
#pragma unroll
    for (int r = 0; r < 16; ++r) s0[r] = __builtin_amdgcn_exp2f(s0[r]);
    {
      float a8[8];
#pragma unroll
      for (int i = 0; i < 8; ++i) a8[i] = s0[2 * i] + s0[2 * i + 1];
      float a4a = a8[0] + a8[1], a4b = a8[2] + a8[3], a4c = a8[4] + a8[5], a4d = a8[6] + a8[7];
      l += (a4a + a4b) + (a4c + a4d);
    }
    unsigned w0[8];
    cvt8(s0, w0);
    union { unsigned u[4]; bf16x8 v; } pf00, pf01;
    pf00.u[0] = w0[0]; pf00.u[1] = w0[1]; pf00.u[2] = w0[2]; pf00.u[3] = w0[3];
    pf01.u[0] = w0[4]; pf01.u[1] = w0[5]; pf01.u[2] = w0[6]; pf01.u[3] = w0[7];

    // ---- QK1: S^T half 1 (keys kb=1)
    f32x16 s1 = {};
#pragma unroll
    for (int t = 0; t < 4; ++t) {
      bf16x8 kf = *(const bf16x8*)(Lp + 4096 + koff[t]);
      s1 = __builtin_amdgcn_mfma_f32_32x32x16_bf16(kf, aq[t], s1, 0, 0, 0);
    }

    // ---- PV0 (matrix pipe) — overlaps exp2/cvt 1 below (no data deps)
    {
      bf16x8 v0 = *(const bf16x8*)(Vp + voff[0][0]);
      bf16x8 v1 = *(const bf16x8*)(Vp + voff[0][1]);
      bf16x8 u0 = *(const bf16x8*)(Vp + 4096 + voff[0][0]);
      bf16x8 u1 = *(const bf16x8*)(Vp + 4096 + voff[0][1]);
      oacc0 = __builtin_amdgcn_mfma_f32_32x32x16_bf16(pf00.v, v0, oacc0, 0, 0, 0);
      oacc0 = __builtin_amdgcn_mfma_f32_32x32x16_bf16(pf01.v, v1, oacc0, 0, 0, 0);
      oacc1 = __builtin_amdgcn_mfma_f32_32x32x16_bf16(pf00.v, u0, oacc1, 0, 0, 0);
      oacc1 = __builtin_amdgcn_mfma_f32_32x32x16_bf16(pf01.v, u1, oacc1, 0, 0, 0);
    }

    // ---- exp2 + l-tree + cvt 1 (VALU/trans — schedulable against PV0)
#pragma unroll
    for (int r = 0; r < 16; ++r) s1[r] = __builtin_amdgcn_exp2f(s1[r]);
    {
      float a8[8];
#pragma unroll
      for (int i = 0; i < 8; ++i) a8[i] = s1[2 * i] + s1[2 * i + 1];
      float a4a = a8[0] + a8[1], a4b = a8[2] + a8[3], a4c = a8[4] + a8[5], a4d = a8[6] + a8[7];
      l += (a4a + a4b) + (a4c + a4d);
    }
    unsigned w1[8];
    cvt8(s1, w1);
    union { unsigned u[4]; bf16x8 v; } pf10, pf11;
    pf10.u[0] = w1[0]; pf10.u[1] = w1[1]; pf10.u[2] = w1[2]; pf10.u[3] = w1[3];
    pf11.u[0] = w1[4]; pf11.u[1] = w1[5]; pf11.u[2] = w1[6]; pf11.u[3] = w1[7];

    // ---- PV1
    {
      bf16x8 v0 = *(const bf16x8*)(Vp + voff[1][0]);
      bf16x8 v1 = *(const bf16x8*)(Vp + voff[1][1]);
      bf16x8 u0 = *(const bf16x8*)(Vp + 4096 + voff[1][0]);
      bf16x8 u1 = *(const bf16x8*)(Vp + 4096 + voff[1][1]);
      oacc0 = __builtin_amdgcn_mfma_f32_32x32x16_bf16(pf10.v, v0, oacc0, 0, 0, 0);
      oacc0 = __builtin_amdgcn_mfma_f32_32x32x16_bf16(pf11.v, v1, oacc0, 0, 0, 0);
      oacc1 = __builtin_amdgcn_mfma_f32_32x32x16_bf16(pf10.v, u0, oacc1, 0, 0, 0);
      oacc1 = __builtin_amdgcn_mfma_f32_32x32x16_bf16(pf11.v, u1, oacc1, 0, 0, 0);
    }

    __syncthreads();
    buf ^= 1;
  }

  // combine the two key-halves of l once
  l += __shfl_xor(l, 32, 64);

  // epilogue: O[b][t][h*64+d], d = db*32 + l31, t rows via D-layout
#pragma unroll
  for (int r = 0; r < 16; ++r) {
    float lt = __shfl(l, ((r & 3) + 8 * (r >> 2)) + 4 * hi, 64);
    float inv = 1.0f / lt;
    int t = q0 + ((r & 3) + 8 * (r >> 2)) + 4 * hi;
    size_t rowb = (size_t)(b * T_SEQ + t) * CDIM + h * 64;
    O[rowb + l31]      = f2bf(oacc0[r] * inv);
    O[rowb + 32 + l31] = f2bf(oacc1[r] * inv);
  }
}

// ---------------- kernel 5: proj GEMM  [8192][768] @ [768][768] + bias -> f32 ----------------
__global__ __launch_bounds__(256) void k_proj(const unsigned short* __restrict__ A,
                                              const unsigned short* __restrict__ Bt,
                                              const float* __restrict__ bias,
                                              float* __restrict__ out) {
  __shared__ short As[128 * 64];
  __shared__ short Bs[128 * 64];
  const int tid = threadIdx.x;
  const int wave = tid >> 6, lane = tid & 63;
  const int wr = wave >> 1, wc = wave & 1;
  // XCD-aware swizzle (m204, 384 = 8*48)
  const int lin = blockIdx.y * 6 + blockIdx.x;
  const int wg = (lin & 7) * 48 + (lin >> 3);
  const int m0 = (wg / 6) * 128, n0 = (wg % 6) * 128;

  f32x4 acc[4][4] = {};

#pragma unroll 1
  for (int k0 = 0; k0 < 768; k0 += 64) {
#pragma unroll
    for (int it = 0; it < 4; ++it) {
      int chunk = wave * 4 + it;
      int slot = chunk * 64 + lane;
      int row = slot >> 3, j = slot & 7;
      int kcol = k0 + ((j ^ (row & 7)) << 3);
      gld_lds16(A  + (size_t)(m0 + row) * 768 + kcol, &As[chunk * 512]);
      gld_lds16(Bt + (size_t)(n0 + row) * 768 + kcol, &Bs[chunk * 512]);
    }
    __syncthreads();
#pragma unroll
    for (int kk = 0; kk < 2; ++kk) {
      bf16x8 af[4], bfr[4];
      int cbl = kk * 4 + (lane >> 4);
#pragma unroll
      for (int mi = 0; mi < 4; ++mi) {
        int row = wr * 64 + mi * 16 + (lane & 15);
        af[mi] = *(const bf16x8*)&As[(row * 8 + (cbl ^ (row & 7))) * 8];
      }
#pragma unroll
      for (int ni = 0; ni < 4; ++ni) {
        int row = wc * 64 + ni * 16 + (lane & 15);
        bfr[ni] = *(const bf16x8*)&Bs[(row * 8 + (cbl ^ (row & 7))) * 8];
      }
#pragma unroll
      for (int mi = 0; mi < 4; ++mi)
#pragma unroll
        for (int ni = 0; ni < 4; ++ni)
          acc[mi][ni] = __builtin_amdgcn_mfma_f32_16x16x32_bf16(af[mi], bfr[ni], acc[mi][ni], 0, 0, 0);
    }
    __syncthreads();
  }

#pragma unroll
  for (int ni = 0; ni < 4; ++ni) {
    int col = n0 + wc * 64 + ni * 16 + (lane & 15);
    float bi = bias[col];
#pragma unroll
    for (int mi = 0; mi < 4; ++mi) {
      int mt = m0 + wr * 64 + mi * 16 + ((lane >> 4) << 2);
#pragma unroll
      for (int r = 0; r < 4; ++r)
        out[(size_t)(mt + r) * CDIM + col] = acc[mi][ni][r] + bi;
    }
  }
}

extern "C" void kernel_launch(void* const* d_in, const int* in_sizes, int n_in,
                              void* d_out, int out_size, void* d_ws, size_t ws_size,
                              hipStream_t stream) {
  const float* x  = (const float*)d_in[0];
  const float* Wa = (const float*)d_in[1];
  const float* ba = (const float*)d_in[2];
  const float* Wp = (const float*)d_in[3];
  const float* bp = (const float*)d_in[4];

  char* ws = (char*)d_ws;
  unsigned short* xb  = (unsigned short*)(ws + OFF_XB);
  unsigned short* WaT = (unsigned short*)(ws + OFF_WAT);
  unsigned short* WpT = (unsigned short*)(ws + OFF_WPT);
  unsigned short* Qb  = (unsigned short*)(ws + OFF_Q);
  unsigned short* Kb  = (unsigned short*)(ws + OFF_K);
  unsigned short* Vtb = (unsigned short*)(ws + OFF_VT);
  unsigned short* Ob  = (unsigned short*)(ws + OFF_O);

  k_conv<<<3072, 256, 0, stream>>>(x, xb);
  k_transpose<<<dim3(36, 12), 256, 0, stream>>>(Wa, WaT, CDIM, 3 * CDIM);
  k_transpose<<<dim3(12, 12), 256, 0, stream>>>(Wp, WpT, CDIM, CDIM);
  k_qkv<<<dim3(18, 64), 256, 0, stream>>>(xb, WaT, ba, Qb, Kb, Vtb);
  k_attn<<<dim3(32, 24), 256, 0, stream>>>(Qb, Kb, Vtb, Ob);
  k_proj<<<dim3(6, 64), 256, 0, stream>>>(Ob, WpT, bp, (float*)d_out);
}